// Round 6
// baseline (347.731 us; speedup 1.0000x reference)
//
#include <hip/hip_runtime.h>
#include <hip/hip_bf16.h>

#define D 64
#define NB_CNT 1024          // blocks for edge-streaming kernels

typedef float vfloat4 __attribute__((ext_vector_type(4)));
typedef short short8 __attribute__((ext_vector_type(8)));
typedef float f32x4 __attribute__((ext_vector_type(4)));

__device__ __forceinline__ unsigned short f2bf(float f) {
    union { float f; unsigned u; } v; v.f = f;
    unsigned r = (v.u + 0x7FFF + ((v.u >> 16) & 1)) >> 16;   // RNE
    return (unsigned short)r;
}
__device__ __forceinline__ unsigned short bftrunc(float f) {
    union { float f; unsigned u; } v; v.f = f;
    return (unsigned short)(v.u >> 16);                      // truncate (hi part of split)
}
__device__ __forceinline__ float bffrom(unsigned short h) {
    union { unsigned u; float f; } v; v.u = ((unsigned)h) << 16; return v.f;
}
__device__ __forceinline__ float bflo(unsigned u) {
    union { unsigned u; float f; } v; v.u = u << 16; return v.f;
}
__device__ __forceinline__ float bfhi(unsigned u) {
    union { unsigned u; float f; } v; v.u = u & 0xFFFF0000u; return v.f;
}

// =============== k1: per-node in-degree count (global atomics) + W-fragment precompute ===============
// blocks [0, NB_CNT): deg[dst]++ over the edge list.  blocks [NB_CNT, NB_CNT+4): build MFMA
// B-fragments of W1/W2 split into bf16 hi/lo (layout: lane l supplies col=16c+(l&15),
// k = 32s + 8(l>>4) + j; stored Wf[combo*512 + lane*8 + j] -> one coalesced 16B load per lane).
__global__ __launch_bounds__(256) void count_wfrag(
    const int* __restrict__ dst, int E, int* __restrict__ deg,
    const float* __restrict__ W1, const float* __restrict__ W2,
    unsigned short* __restrict__ WfH1, unsigned short* __restrict__ WfL1,
    unsigned short* __restrict__ WfH2, unsigned short* __restrict__ WfL2)
{
    int tid = threadIdx.x;

    if ((int)blockIdx.x < NB_CNT) {
        int stride = NB_CNT * 1024;
        for (int i = ((int)blockIdx.x * 256 + tid) * 4; i < E; i += stride) {
            if (i + 3 < E) {
                int4 d4 = *(const int4*)(dst + i);
                atomicAdd(&deg[d4.x], 1);
                atomicAdd(&deg[d4.y], 1);
                atomicAdd(&deg[d4.z], 1);
                atomicAdd(&deg[d4.w], 1);
            } else {
                for (int k = i; k < E; ++k) atomicAdd(&deg[dst[k]], 1);
            }
        }
        return;
    }

    int b = (int)blockIdx.x - NB_CNT;
    const float* Wsrc = (b >> 1) ? W2 : W1;
    unsigned short* fh = (b >> 1) ? WfH2 : WfH1;
    unsigned short* fl = (b >> 1) ? WfL2 : WfL1;
    int combo = (b & 1) * 4 + (tid >> 6);
    int lane = tid & 63;
    int s = combo >> 2, c = combo & 3, g = lane >> 4, rl = lane & 15;
#pragma unroll
    for (int j = 0; j < 8; ++j) {
        float v = Wsrc[(32 * s + 8 * g + j) * D + 16 * c + rl];
        unsigned short h = bftrunc(v);
        fh[combo * 512 + lane * 8 + j] = h;
        fl[combo * 512 + lane * 8 + j] = f2bf(v - bffrom(h));
    }
}

// =============== k2a: per-block (2048-entry) sums of deg ===============
__global__ __launch_bounds__(256) void scan_sums(
    const int* __restrict__ deg, int* __restrict__ bsum, int N)
{
    __shared__ int wsum[4];
    int tid = threadIdx.x, lane = tid & 63, wave = tid >> 6;
    int base = (int)blockIdx.x * 2048 + tid * 8;
    int s = 0;
#pragma unroll
    for (int k = 0; k < 8; ++k) {
        int i = base + k;
        if (i < N) s += deg[i];
    }
    for (int d = 32; d >= 1; d >>= 1) s += __shfl_xor(s, d, 64);
    if (lane == 0) wsum[wave] = s;
    __syncthreads();
    if (tid == 0) bsum[blockIdx.x] = wsum[0] + wsum[1] + wsum[2] + wsum[3];
}

// =============== k2b: full exclusive scan -> ofs (+ cur copy + dinv) ===============
// Each block re-scans the (<=64) block sums in one wave for its base, then block-scans
// its own 2048 entries.  SB = number of scan blocks (<= 64 for N <= 131072).
__global__ __launch_bounds__(256) void scan_write(
    const int* __restrict__ deg, const int* __restrict__ bsum,
    int* __restrict__ ofs, int* __restrict__ cur, float* __restrict__ dinv,
    int N, int SB)
{
    __shared__ int sBase;
    __shared__ int wsum[4];
    int tid = threadIdx.x, lane = tid & 63, wave = tid >> 6;

    if (wave == 0) {
        int v = (lane < SB) ? bsum[lane] : 0;
        int inc = v;
        for (int d = 1; d < 64; d <<= 1) {
            int t = __shfl_up(inc, d, 64);
            if (lane >= d) inc += t;
        }
        if (lane == (int)blockIdx.x) sBase = inc - v;
    }

    int base = (int)blockIdx.x * 2048 + tid * 8;
    int v[8], p[8], t8 = 0;
#pragma unroll
    for (int k = 0; k < 8; ++k) {
        int i = base + k;
        v[k] = (i < N) ? deg[i] : 0;
        p[k] = t8;
        t8 += v[k];
    }
    int inc = t8;
    for (int d = 1; d < 64; d <<= 1) {
        int t = __shfl_up(inc, d, 64);
        if (lane >= d) inc += t;
    }
    if (lane == 63) wsum[wave] = inc;
    __syncthreads();

    int wbase = 0;
    for (int w = 0; w < wave; ++w) wbase += wsum[w];
    int ebase = sBase + wbase + inc - t8;
#pragma unroll
    for (int k = 0; k < 8; ++k) {
        int i = base + k;
        if (i < N) {
            int o = ebase + p[k];
            ofs[i] = o;
            cur[i] = o;
            dinv[i] = rsqrtf((float)v[k] + 1.0f);
        }
    }
}

// =============== k3: scatter edges into CSR via global cursors ===============
// Entry order within a node is nondeterministic (atomic race) -- aggregation sums are
// order-independent to ~1 ulp fp32, far below the output tolerance.
__global__ __launch_bounds__(256) void scatter_csr(
    const int* __restrict__ src, const int* __restrict__ dst,
    int* __restrict__ cur, int* __restrict__ csr, int E)
{
    int stride = NB_CNT * 1024;
    for (int i = ((int)blockIdx.x * 256 + threadIdx.x) * 4; i < E; i += stride) {
        if (i + 3 < E) {
            int4 d4 = *(const int4*)(dst + i);
            int4 s4 = *(const int4*)(src + i);
            csr[atomicAdd(&cur[d4.x], 1)] = s4.x;
            csr[atomicAdd(&cur[d4.y], 1)] = s4.y;
            csr[atomicAdd(&cur[d4.z], 1)] = s4.z;
            csr[atomicAdd(&cur[d4.w], 1)] = s4.w;
        } else {
            for (int k = i; k < E; ++k) csr[atomicAdd(&cur[dst[k]], 1)] = src[k];
        }
    }
}

// =============== GEMM1 (MFMA): hn = bf16((X @ W1) * dinv[row]) ===============
// 3-term split product: Xhi*Whi + Xhi*Wlo + Xlo*Whi  (~fp32 accuracy).
__global__ __launch_bounds__(256) void gemm1_mfma(
    const float* __restrict__ X,
    const unsigned short* __restrict__ WfH, const unsigned short* __restrict__ WfL,
    const float* __restrict__ dinv, unsigned short* __restrict__ hn, int N)
{
    int t = threadIdx.x, wave = t >> 6, lane = t & 63;
    int rowBase = (int)blockIdx.x * 64 + wave * 16;
    if (rowBase >= N) return;
    int g = lane >> 4, rl = lane & 15;

    short8 BH[2][4], BL[2][4];
#pragma unroll
    for (int s = 0; s < 2; ++s)
#pragma unroll
        for (int c = 0; c < 4; ++c) {
            BH[s][c] = *(const short8*)(WfH + ((s * 4 + c) * 64 + lane) * 8);
            BL[s][c] = *(const short8*)(WfL + ((s * 4 + c) * 64 + lane) * 8);
        }

    int arow = rowBase + rl; if (arow >= N) arow = N - 1;
    const float* xr = X + (size_t)arow * D;

    f32x4 acc[4];
#pragma unroll
    for (int c = 0; c < 4; ++c) acc[c] = (f32x4){0.f, 0.f, 0.f, 0.f};

#pragma unroll
    for (int s = 0; s < 2; ++s) {
        vfloat4 x0 = *(const vfloat4*)(xr + 32 * s + 8 * g);
        vfloat4 x1 = *(const vfloat4*)(xr + 32 * s + 8 * g + 4);
        short8 ah, al;
#pragma unroll
        for (int j = 0; j < 4; ++j) {
            unsigned short h0 = bftrunc(x0[j]);
            ah[j] = (short)h0; al[j] = (short)f2bf(x0[j] - bffrom(h0));
            unsigned short h1 = bftrunc(x1[j]);
            ah[j + 4] = (short)h1; al[j + 4] = (short)f2bf(x1[j] - bffrom(h1));
        }
#pragma unroll
        for (int c = 0; c < 4; ++c)
            acc[c] = __builtin_amdgcn_mfma_f32_16x16x32_bf16(ah, BH[s][c], acc[c], 0, 0, 0);
#pragma unroll
        for (int c = 0; c < 4; ++c)
            acc[c] = __builtin_amdgcn_mfma_f32_16x16x32_bf16(ah, BL[s][c], acc[c], 0, 0, 0);
#pragma unroll
        for (int c = 0; c < 4; ++c)
            acc[c] = __builtin_amdgcn_mfma_f32_16x16x32_bf16(al, BH[s][c], acc[c], 0, 0, 0);
    }

#pragma unroll
    for (int r = 0; r < 4; ++r) {
        int row = rowBase + g * 4 + r;
        if (row < N) {
            float dv = dinv[row];
            unsigned short* hr = hn + (size_t)row * D + rl;
#pragma unroll
            for (int c = 0; c < 4; ++c) hr[c * 16] = f2bf(acc[c][r] * dv);
        }
    }
}

// =============== fused agg1 + GEMM2: hn2 = bf16((relu(agg(hn)+b1) @ W2) * dinv[row]) ===============
// Phase 1: aggregate 32 nodes (8-lane groups, depth-4 gather pipeline) -> LDS bf16 tile.
// Phase 2: waves 0,1 each do one 16x64 MFMA tile (W2 split hi/lo), scale by dinv, write hn2.
// LDS row stride 72 shorts (144 B) -> frag reads land on distinct banks (only free 2-way alias).
__global__ __launch_bounds__(256) void agg1_gemm2(
    const int* __restrict__ ofs, const int* __restrict__ deg,
    const int* __restrict__ csr, const unsigned short* __restrict__ hnA,
    const float* __restrict__ dinv, const float* __restrict__ bias,
    const unsigned short* __restrict__ WfH, const unsigned short* __restrict__ WfL,
    unsigned short* __restrict__ hnB, int N)
{
    __shared__ unsigned short sH[32 * 72];
    int tid  = threadIdx.x;
    int lane = tid & 63, wave = tid >> 6;
    int grp  = lane >> 3, sub = lane & 7;
    int rowInBlk = wave * 8 + grp;
    int nodeBase = (int)blockIdx.x * 32;
    int node = nodeBase + rowInBlk;
    bool live = (node < N);

    const int4* hrow = (const int4*)hnA;
    float2 a0 = {0.f, 0.f}, a1 = {0.f, 0.f}, a2 = {0.f, 0.f}, a3 = {0.f, 0.f};

    int s0 = 0, cnt = 0;
    if (live) {
        s0  = ofs[node];
        cnt = deg[node];
        int4 h = hrow[(size_t)node * 8 + sub];       // self loop (pre-scaled)
        a0.x += bflo(h.x); a0.y += bfhi(h.x);
        a1.x += bflo(h.y); a1.y += bfhi(h.y);
        a2.x += bflo(h.z); a2.y += bfhi(h.z);
        a3.x += bflo(h.w); a3.y += bfhi(h.w);
    }

    const int* cp = csr + s0;
    int j = 0;
    for (; j + 3 < cnt; j += 4) {                    // 4 gathers in flight per lane
        int sA = cp[j], sB = cp[j + 1], sC = cp[j + 2], sD = cp[j + 3];
        int4 hA = hrow[(size_t)sA * 8 + sub];
        int4 hB = hrow[(size_t)sB * 8 + sub];
        int4 hC = hrow[(size_t)sC * 8 + sub];
        int4 hD = hrow[(size_t)sD * 8 + sub];
        a0.x += bflo(hA.x); a0.y += bfhi(hA.x);
        a1.x += bflo(hA.y); a1.y += bfhi(hA.y);
        a2.x += bflo(hA.z); a2.y += bfhi(hA.z);
        a3.x += bflo(hA.w); a3.y += bfhi(hA.w);
        a0.x += bflo(hB.x); a0.y += bfhi(hB.x);
        a1.x += bflo(hB.y); a1.y += bfhi(hB.y);
        a2.x += bflo(hB.z); a2.y += bfhi(hB.z);
        a3.x += bflo(hB.w); a3.y += bfhi(hB.w);
        a0.x += bflo(hC.x); a0.y += bfhi(hC.x);
        a1.x += bflo(hC.y); a1.y += bfhi(hC.y);
        a2.x += bflo(hC.z); a2.y += bfhi(hC.z);
        a3.x += bflo(hC.w); a3.y += bfhi(hC.w);
        a0.x += bflo(hD.x); a0.y += bfhi(hD.x);
        a1.x += bflo(hD.y); a1.y += bfhi(hD.y);
        a2.x += bflo(hD.z); a2.y += bfhi(hD.z);
        a3.x += bflo(hD.w); a3.y += bfhi(hD.w);
    }
    for (; j < cnt; ++j) {
        int sA = cp[j];
        int4 hA = hrow[(size_t)sA * 8 + sub];
        a0.x += bflo(hA.x); a0.y += bfhi(hA.x);
        a1.x += bflo(hA.y); a1.y += bfhi(hA.y);
        a2.x += bflo(hA.z); a2.y += bfhi(hA.z);
        a3.x += bflo(hA.w); a3.y += bfhi(hA.w);
    }

    {
        float dw = live ? dinv[node] : 0.f;
        float4 b0 = ((const float4*)bias)[sub * 2];
        float4 b1 = ((const float4*)bias)[sub * 2 + 1];
        float o0 = fmaxf(a0.x * dw + b0.x, 0.f);
        float o1 = fmaxf(a0.y * dw + b0.y, 0.f);
        float o2 = fmaxf(a1.x * dw + b0.z, 0.f);
        float o3 = fmaxf(a1.y * dw + b0.w, 0.f);
        float o4 = fmaxf(a2.x * dw + b1.x, 0.f);
        float o5 = fmaxf(a2.y * dw + b1.y, 0.f);
        float o6 = fmaxf(a3.x * dw + b1.z, 0.f);
        float o7 = fmaxf(a3.y * dw + b1.w, 0.f);
        unsigned r0 = (unsigned)f2bf(o0) | ((unsigned)f2bf(o1) << 16);
        unsigned r1 = (unsigned)f2bf(o2) | ((unsigned)f2bf(o3) << 16);
        unsigned r2 = (unsigned)f2bf(o4) | ((unsigned)f2bf(o5) << 16);
        unsigned r3 = (unsigned)f2bf(o6) | ((unsigned)f2bf(o7) << 16);
        *(int4*)&sH[rowInBlk * 72 + sub * 8] = make_int4((int)r0, (int)r1, (int)r2, (int)r3);
    }
    __syncthreads();

    if (wave < 2) {
        int g = lane >> 4, rl = lane & 15;
        f32x4 acc[4];
#pragma unroll
        for (int c = 0; c < 4; ++c) acc[c] = (f32x4){0.f, 0.f, 0.f, 0.f};

#pragma unroll
        for (int s = 0; s < 2; ++s) {
            short8 a = *(const short8*)&sH[(wave * 16 + rl) * 72 + 32 * s + 8 * g];
            short8 BH[4], BL[4];
#pragma unroll
            for (int c = 0; c < 4; ++c) {
                BH[c] = *(const short8*)(WfH + ((s * 4 + c) * 64 + lane) * 8);
                BL[c] = *(const short8*)(WfL + ((s * 4 + c) * 64 + lane) * 8);
            }
#pragma unroll
            for (int c = 0; c < 4; ++c)
                acc[c] = __builtin_amdgcn_mfma_f32_16x16x32_bf16(a, BH[c], acc[c], 0, 0, 0);
#pragma unroll
            for (int c = 0; c < 4; ++c)
                acc[c] = __builtin_amdgcn_mfma_f32_16x16x32_bf16(a, BL[c], acc[c], 0, 0, 0);
        }

#pragma unroll
        for (int r = 0; r < 4; ++r) {
            int row = nodeBase + wave * 16 + g * 4 + r;
            if (row < N) {
                float dv = dinv[row];
                unsigned short* hw = hnB + (size_t)row * D + rl;
#pragma unroll
                for (int c = 0; c < 4; ++c) hw[c * 16] = f2bf(acc[c][r] * dv);
            }
        }
    }
}

// =============== aggregate 2: one 8-lane group per node, 8 nodes per wave -> fp32 out ===============
__global__ __launch_bounds__(256) void aggregate_relu_f32(
    const int* __restrict__ ofs, const int* __restrict__ deg,
    const int* __restrict__ csr, const unsigned short* __restrict__ hn,
    const float* __restrict__ dinv, const float* __restrict__ bias,
    float* __restrict__ outF, int N)
{
    int t    = blockIdx.x * 256 + threadIdx.x;
    int lane = threadIdx.x & 63;
    int grp  = lane >> 3, sub = lane & 7;
    int node = (t >> 6) * 8 + grp;
    bool live = (node < N);

    const int4* hrow = (const int4*)hn;
    float2 a0 = {0.f, 0.f}, a1 = {0.f, 0.f}, a2 = {0.f, 0.f}, a3 = {0.f, 0.f};

    int s0 = 0, cnt = 0;
    if (live) {
        s0  = ofs[node];
        cnt = deg[node];
        int4 h = hrow[(size_t)node * 8 + sub];       // self loop (pre-scaled)
        a0.x += bflo(h.x); a0.y += bfhi(h.x);
        a1.x += bflo(h.y); a1.y += bfhi(h.y);
        a2.x += bflo(h.z); a2.y += bfhi(h.z);
        a3.x += bflo(h.w); a3.y += bfhi(h.w);
    }

    const int* cp = csr + s0;
    int j = 0;
    for (; j + 3 < cnt; j += 4) {                    // 4 gathers in flight per lane
        int sA = cp[j], sB = cp[j + 1], sC = cp[j + 2], sD = cp[j + 3];
        int4 hA = hrow[(size_t)sA * 8 + sub];
        int4 hB = hrow[(size_t)sB * 8 + sub];
        int4 hC = hrow[(size_t)sC * 8 + sub];
        int4 hD = hrow[(size_t)sD * 8 + sub];
        a0.x += bflo(hA.x); a0.y += bfhi(hA.x);
        a1.x += bflo(hA.y); a1.y += bfhi(hA.y);
        a2.x += bflo(hA.z); a2.y += bfhi(hA.z);
        a3.x += bflo(hA.w); a3.y += bfhi(hA.w);
        a0.x += bflo(hB.x); a0.y += bfhi(hB.x);
        a1.x += bflo(hB.y); a1.y += bfhi(hB.y);
        a2.x += bflo(hB.z); a2.y += bfhi(hB.z);
        a3.x += bflo(hB.w); a3.y += bfhi(hB.w);
        a0.x += bflo(hC.x); a0.y += bfhi(hC.x);
        a1.x += bflo(hC.y); a1.y += bfhi(hC.y);
        a2.x += bflo(hC.z); a2.y += bfhi(hC.z);
        a3.x += bflo(hC.w); a3.y += bfhi(hC.w);
        a0.x += bflo(hD.x); a0.y += bfhi(hD.x);
        a1.x += bflo(hD.y); a1.y += bfhi(hD.y);
        a2.x += bflo(hD.z); a2.y += bfhi(hD.z);
        a3.x += bflo(hD.w); a3.y += bfhi(hD.w);
    }
    for (; j < cnt; ++j) {
        int sA = cp[j];
        int4 hA = hrow[(size_t)sA * 8 + sub];
        a0.x += bflo(hA.x); a0.y += bfhi(hA.x);
        a1.x += bflo(hA.y); a1.y += bfhi(hA.y);
        a2.x += bflo(hA.z); a2.y += bfhi(hA.z);
        a3.x += bflo(hA.w); a3.y += bfhi(hA.w);
    }

    if (live) {
        float dw = dinv[node];
        float4 b0 = ((const float4*)bias)[sub * 2];
        float4 b1 = ((const float4*)bias)[sub * 2 + 1];
        float o0 = fmaxf(a0.x * dw + b0.x, 0.f);
        float o1 = fmaxf(a0.y * dw + b0.y, 0.f);
        float o2 = fmaxf(a1.x * dw + b0.z, 0.f);
        float o3 = fmaxf(a1.y * dw + b0.w, 0.f);
        float o4 = fmaxf(a2.x * dw + b1.x, 0.f);
        float o5 = fmaxf(a2.y * dw + b1.y, 0.f);
        float o6 = fmaxf(a3.x * dw + b1.z, 0.f);
        float o7 = fmaxf(a3.y * dw + b1.w, 0.f);
        float4 v0 = make_float4(o0, o1, o2, o3);
        float4 v1 = make_float4(o4, o5, o6, o7);
        ((float4*)outF)[(size_t)node * 16 + sub * 2]     = v0;
        ((float4*)outF)[(size_t)node * 16 + sub * 2 + 1] = v1;
    }
}

// =============== launcher ===============

extern "C" void kernel_launch(void* const* d_in, const int* in_sizes, int n_in,
                              void* d_out, int out_size, void* d_ws, size_t ws_size,
                              hipStream_t stream) {
    const float* x   = (const float*)d_in[0];
    const int*   ei  = (const int*)d_in[1];   // [2, E] int32
    const float* W1  = (const float*)d_in[2];
    const float* b1  = (const float*)d_in[3];
    const float* W2  = (const float*)d_in[4];
    const float* b2  = (const float*)d_in[5];

    int N = in_sizes[0] / D;
    int E = in_sizes[1] / 2;
    const int* src = ei;
    const int* dst = ei + E;
    int SB = (N + 2047) / 2048;               // scan blocks (<= 64 for N <= 131072)

    // workspace layout (bytes, ~38 MB)
    char* ws = (char*)d_ws;
    int*            deg  = (int*)(ws + 0x00000000);           // N
    float*          dinv = (float*)(ws + 0x00080000);         // N
    int*            ofs  = (int*)(ws + 0x00100000);           // N
    int*            cur  = (int*)(ws + 0x00180000);           // N
    int*            bsum = (int*)(ws + 0x00200000);           // 64
    int*            csr  = (int*)(ws + 0x00210000);           // E (6.4 MB)
    unsigned short* hnA  = (unsigned short*)(ws + 0x00A40000);// N*D bf16 (12.8 MB)
    unsigned short* hnB  = (unsigned short*)(ws + 0x01700000);// N*D bf16 (12.8 MB)
    unsigned short* WfH1 = (unsigned short*)(ws + 0x023C0000);// 4096 ushort each
    unsigned short* WfL1 = WfH1 + 4096;
    unsigned short* WfH2 = WfL1 + 4096;
    unsigned short* WfL2 = WfH2 + 4096;
    float*          outF = (float*)d_out;

    int nb_G = (N + 63) / 64;                 // MFMA gemm: 64 rows/block
    int nb_A = (N + 31) / 32;                 // agg: 8 nodes/wave, 32/block

    hipMemsetAsync(deg, 0, (size_t)N * 4, stream);
    count_wfrag<<<NB_CNT + 4, 256, 0, stream>>>(dst, E, deg, W1, W2, WfH1, WfL1, WfH2, WfL2);
    scan_sums<<<SB, 256, 0, stream>>>(deg, bsum, N);
    scan_write<<<SB, 256, 0, stream>>>(deg, bsum, ofs, cur, dinv, N, SB);
    scatter_csr<<<NB_CNT, 256, 0, stream>>>(src, dst, cur, csr, E);

    // layer 1 GEMM with fused dinv[src] pre-scale
    gemm1_mfma<<<nb_G, 256, 0, stream>>>(x, WfH1, WfL1, dinv, hnA, N);
    // fused: layer-1 aggregate + relu + layer-2 GEMM (+ dinv pre-scale) -> hnB
    agg1_gemm2<<<nb_A, 256, 0, stream>>>(ofs, deg, csr, hnA, dinv, b1, WfH2, WfL2, hnB, N);
    // layer 2 aggregate -> final out (fp32, d_out)
    aggregate_relu_f32<<<nb_A, 256, 0, stream>>>(ofs, deg, csr, hnB, dinv, b2, outF, N);
}

// Round 7
// 234.203 us; speedup vs baseline: 1.4847x; 1.4847x over previous
//
#include <hip/hip_runtime.h>
#include <hip/hip_bf16.h>

#define D 64
#define NB_HIST 256          // partition blocks (fixed ranges, pass A == pass B)
#define MAXBK 512            // supports N <= 131072 (buckets of 256 nodes)
#define QSHIFT 14            // src bins of 16384 nodes (2 MB bf16 rows) -> per-XCD L2 resident
                             // 8 bins cover N <= 131072

typedef float vfloat4 __attribute__((ext_vector_type(4)));
typedef short short8 __attribute__((ext_vector_type(8)));
typedef float f32x4 __attribute__((ext_vector_type(4)));

__device__ __forceinline__ unsigned short f2bf(float f) {
    union { float f; unsigned u; } v; v.f = f;
    unsigned r = (v.u + 0x7FFF + ((v.u >> 16) & 1)) >> 16;   // RNE
    return (unsigned short)r;
}
__device__ __forceinline__ unsigned short bftrunc(float f) {
    union { float f; unsigned u; } v; v.f = f;
    return (unsigned short)(v.u >> 16);                      // truncate (hi part of split)
}
__device__ __forceinline__ float bffrom(unsigned short h) {
    union { unsigned u; float f; } v; v.u = ((unsigned)h) << 16; return v.f;
}
__device__ __forceinline__ float bflo(unsigned u) {
    union { unsigned u; float f; } v; v.u = u << 16; return v.f;
}
__device__ __forceinline__ float bfhi(unsigned u) {
    union { unsigned u; float f; } v; v.u = u & 0xFFFF0000u; return v.f;
}

// =============== pass A: {per-block LDS bucket histogram} + {W-fragment precompute} ===============
__global__ __launch_bounds__(256) void passA_hist_wfrag(
    const int* __restrict__ dst, int* __restrict__ blockCounts, int E, int per, int NBK,
    const float* __restrict__ W1, const float* __restrict__ W2,
    unsigned short* __restrict__ WfH1, unsigned short* __restrict__ WfL1,
    unsigned short* __restrict__ WfH2, unsigned short* __restrict__ WfL2)
{
    int tid = threadIdx.x;

    if ((int)blockIdx.x < NB_HIST) {
        __shared__ int hist[MAXBK];
        for (int i = tid; i < NBK; i += 256) hist[i] = 0;
        __syncthreads();
        int lo = blockIdx.x * per, hi = min(E, lo + per);   // per % 4 == 0
        for (int i = lo + tid * 4; i < hi; i += 1024) {
            if (i + 3 < hi) {
                int4 d4 = *(const int4*)(dst + i);
                atomicAdd(&hist[d4.x >> 8], 1);
                atomicAdd(&hist[d4.y >> 8], 1);
                atomicAdd(&hist[d4.z >> 8], 1);
                atomicAdd(&hist[d4.w >> 8], 1);
            } else {
                for (int k = i; k < hi; ++k) atomicAdd(&hist[dst[k] >> 8], 1);
            }
        }
        __syncthreads();
        for (int i = tid; i < NBK; i += 256)
            blockCounts[(size_t)blockIdx.x * NBK + i] = hist[i];
        return;
    }

    // W-fragment precompute: 4 blocks, block b: w = b>>1 (W1/W2), combos [ (b&1)*4, +4 )
    int b = (int)blockIdx.x - NB_HIST;
    const float* Wsrc = (b >> 1) ? W2 : W1;
    unsigned short* fh = (b >> 1) ? WfH2 : WfH1;
    unsigned short* fl = (b >> 1) ? WfL2 : WfL1;
    int combo = (b & 1) * 4 + (tid >> 6);
    int lane = tid & 63;
    int s = combo >> 2, c = combo & 3, g = lane >> 4, rl = lane & 15;
#pragma unroll
    for (int j = 0; j < 8; ++j) {
        float v = Wsrc[(32 * s + 8 * g + j) * D + 16 * c + rl];
        unsigned short h = bftrunc(v);
        fh[combo * 512 + lane * 8 + j] = h;
        fl[combo * 512 + lane * 8 + j] = f2bf(v - bffrom(h));
    }
}

// =============== C1: per-bucket exclusive scan over the 256 blocks ===============
__global__ __launch_bounds__(256) void scan_cols(
    const int* __restrict__ blockCounts, int* __restrict__ partial,
    int* __restrict__ totals, int NBK)
{
    int wave = threadIdx.x >> 6, lane = threadIdx.x & 63;
    int k = blockIdx.x * 4 + wave;
    if (k >= NBK) return;
    int carry = 0;
    for (int base = 0; base < NB_HIST; base += 64) {
        int b = base + lane;
        int v = blockCounts[(size_t)b * NBK + k];
        int inc = v;
        for (int d = 1; d < 64; d <<= 1) {
            int t = __shfl_up(inc, d, 64);
            if (lane >= d) inc += t;
        }
        partial[(size_t)k * NB_HIST + b] = inc - v + carry;
        carry += __shfl(inc, 63, 64);
    }
    if (lane == 0) totals[k] = carry;
}

// =============== C2: exclusive scan of bucket totals (single wave) ===============
__global__ void scan_buckets(const int* __restrict__ totals, int* __restrict__ bofs, int NBK) {
    int lane = threadIdx.x;
    int carry = 0;
    for (int base = 0; base < NBK; base += 64) {
        int i = base + lane;
        int v = (i < NBK) ? totals[i] : 0;
        int inc = v;
        for (int d = 1; d < 64; d <<= 1) {
            int t = __shfl_up(inc, d, 64);
            if (lane >= d) inc += t;
        }
        if (i < NBK) bofs[i] = inc - v + carry;
        carry += __shfl(inc, 63, 64);
    }
}

// =============== pass B: scatter edges into bucket-grouped order (LDS cursors) ===============
__global__ __launch_bounds__(256) void passB(
    const int* __restrict__ src, const int* __restrict__ dst,
    const int* __restrict__ bofs, const int* __restrict__ partial,
    int* __restrict__ bucketed, int E, int per, int NBK)
{
    __shared__ int cur[MAXBK];
    int tid = threadIdx.x, b = blockIdx.x;
    for (int i = tid; i < NBK; i += 256)
        cur[i] = bofs[i] + partial[(size_t)i * NB_HIST + b];
    __syncthreads();
    int lo = b * per, hi = min(E, lo + per);
    for (int i = lo + tid * 4; i < hi; i += 1024) {
        if (i + 3 < hi) {
            int4 d4 = *(const int4*)(dst + i);
            int4 s4 = *(const int4*)(src + i);
            int p0 = atomicAdd(&cur[d4.x >> 8], 1);
            int p1 = atomicAdd(&cur[d4.y >> 8], 1);
            int p2 = atomicAdd(&cur[d4.z >> 8], 1);
            int p3 = atomicAdd(&cur[d4.w >> 8], 1);
            bucketed[p0] = (s4.x << 8) | (d4.x & 255);
            bucketed[p1] = (s4.y << 8) | (d4.y & 255);
            bucketed[p2] = (s4.z << 8) | (d4.z & 255);
            bucketed[p3] = (s4.w << 8) | (d4.w & 255);
        } else {
            for (int k = i; k < hi; ++k) {
                int d = dst[k], s = src[k];
                int pos = atomicAdd(&cur[d >> 8], 1);
                bucketed[pos] = (s << 8) | (d & 255);
            }
        }
    }
}

// =============== level 2: per-bucket CSR build (src-bin-grouped) + deg/dinv/ofs/qcnt ===============
// Each node's neighbor list in csr is grouped by src bin (src >> QSHIFT, 8 bins).
// qcnt[node] packs the 8 per-bin counts as 8x8 bits (Poisson(2) per bin; overflow prob ~0).
__global__ __launch_bounds__(256) void build_csr(
    const int* __restrict__ bucketed, const int* __restrict__ bofs,
    const int* __restrict__ totals, int* __restrict__ deg, float* __restrict__ dinv,
    int* __restrict__ ofs, int2* __restrict__ qcnt, int* __restrict__ csr, int N)
{
    __shared__ int h8[256 * 8];     // per-node per-bin counts, later reused as cursors
    __shared__ int scn[256];
    int tid = threadIdx.x, k = blockIdx.x;
    int e0 = bofs[k], e1 = e0 + totals[k];
    int node = k * 256 + tid;

    for (int i = tid; i < 2048; i += 256) h8[i] = 0;
    __syncthreads();
    for (int i = e0 + tid; i < e1; i += 256) {
        int v = bucketed[i];
        atomicAdd(&h8[(v & 255) * 8 + ((v >> 8) >> QSHIFT)], 1);
    }
    __syncthreads();

    int c[8]; int mydeg = 0;
#pragma unroll
    for (int b = 0; b < 8; ++b) { c[b] = h8[tid * 8 + b]; mydeg += c[b]; }
    scn[tid] = mydeg;
    __syncthreads();
    for (int d2 = 1; d2 < 256; d2 <<= 1) {
        int t = (tid >= d2) ? scn[tid - d2] : 0;
        __syncthreads();
        scn[tid] += t;
        __syncthreads();
    }
    int myofs = scn[tid] - mydeg;

    if (node < N) {
        deg[node]  = mydeg;
        dinv[node] = rsqrtf((float)(mydeg + 1));
        ofs[node]  = e0 + myofs;
        int lo = c[0] | (c[1] << 8) | (c[2] << 16) | (c[3] << 24);
        int hi = c[4] | (c[5] << 8) | (c[6] << 16) | (c[7] << 24);
        qcnt[node] = make_int2(lo, hi);
    }

    // per-node per-bin write cursors
    int run = myofs;
#pragma unroll
    for (int b = 0; b < 8; ++b) { h8[tid * 8 + b] = run; run += c[b]; }
    __syncthreads();
    for (int i = e0 + tid; i < e1; i += 256) {
        int v = bucketed[i];
        int s = v >> 8;
        int pos = atomicAdd(&h8[(v & 255) * 8 + (s >> QSHIFT)], 1);
        csr[e0 + pos] = s;
    }
}

// =============== GEMM1 (MFMA): hn = bf16((X @ W1) * dinv[row]) ===============
__global__ __launch_bounds__(256) void gemm1_mfma(
    const float* __restrict__ X,
    const unsigned short* __restrict__ WfH, const unsigned short* __restrict__ WfL,
    const float* __restrict__ dinv, unsigned short* __restrict__ hn, int N)
{
    int t = threadIdx.x, wave = t >> 6, lane = t & 63;
    int rowBase = (int)blockIdx.x * 64 + wave * 16;
    if (rowBase >= N) return;
    int g = lane >> 4, rl = lane & 15;

    short8 BH[2][4], BL[2][4];
#pragma unroll
    for (int s = 0; s < 2; ++s)
#pragma unroll
        for (int c = 0; c < 4; ++c) {
            BH[s][c] = *(const short8*)(WfH + ((s * 4 + c) * 64 + lane) * 8);
            BL[s][c] = *(const short8*)(WfL + ((s * 4 + c) * 64 + lane) * 8);
        }

    int arow = rowBase + rl; if (arow >= N) arow = N - 1;
    const float* xr = X + (size_t)arow * D;

    f32x4 acc[4];
#pragma unroll
    for (int c = 0; c < 4; ++c) acc[c] = (f32x4){0.f, 0.f, 0.f, 0.f};

#pragma unroll
    for (int s = 0; s < 2; ++s) {
        vfloat4 x0 = *(const vfloat4*)(xr + 32 * s + 8 * g);
        vfloat4 x1 = *(const vfloat4*)(xr + 32 * s + 8 * g + 4);
        short8 ah, al;
#pragma unroll
        for (int j = 0; j < 4; ++j) {
            unsigned short h0 = bftrunc(x0[j]);
            ah[j] = (short)h0; al[j] = (short)f2bf(x0[j] - bffrom(h0));
            unsigned short h1 = bftrunc(x1[j]);
            ah[j + 4] = (short)h1; al[j + 4] = (short)f2bf(x1[j] - bffrom(h1));
        }
#pragma unroll
        for (int c = 0; c < 4; ++c)
            acc[c] = __builtin_amdgcn_mfma_f32_16x16x32_bf16(ah, BH[s][c], acc[c], 0, 0, 0);
#pragma unroll
        for (int c = 0; c < 4; ++c)
            acc[c] = __builtin_amdgcn_mfma_f32_16x16x32_bf16(ah, BL[s][c], acc[c], 0, 0, 0);
#pragma unroll
        for (int c = 0; c < 4; ++c)
            acc[c] = __builtin_amdgcn_mfma_f32_16x16x32_bf16(al, BH[s][c], acc[c], 0, 0, 0);
    }

#pragma unroll
    for (int r = 0; r < 4; ++r) {
        int row = rowBase + g * 4 + r;
        if (row < N) {
            float dv = dinv[row];
            unsigned short* hr = hn + (size_t)row * D + rl;
#pragma unroll
            for (int c = 0; c < 4; ++c) hr[c * 16] = f2bf(acc[c][r] * dv);
        }
    }
}

// gather-accumulate macros (int4 = 8 bf16 of the row chunk owned by this lane)
#define ACC1(h)                                   \
    a0.x += bflo((h).x); a0.y += bfhi((h).x);     \
    a1.x += bflo((h).y); a1.y += bfhi((h).y);     \
    a2.x += bflo((h).z); a2.y += bfhi((h).z);     \
    a3.x += bflo((h).w); a3.y += bfhi((h).w);

// bin-phased gather loop over one node's csr list (8 src bins, counts packed in qlo/qhi)
#define BIN_GATHER_LOOP                                                   \
    for (int bb = 0; bb < 8; ++bb) {                                      \
        int cnt = (int)(qlo & 255u);                                      \
        qlo = (qlo >> 8) | (qhi << 24);                                   \
        qhi >>= 8;                                                        \
        int j = 0;                                                        \
        for (; j + 3 < cnt; j += 4) {                                     \
            int sA = cp[j], sB = cp[j + 1], sC = cp[j + 2], sD = cp[j + 3]; \
            int4 hA = hrow[(size_t)sA * 8 + sub];                         \
            int4 hB = hrow[(size_t)sB * 8 + sub];                         \
            int4 hC = hrow[(size_t)sC * 8 + sub];                         \
            int4 hD = hrow[(size_t)sD * 8 + sub];                         \
            ACC1(hA); ACC1(hB); ACC1(hC); ACC1(hD);                       \
        }                                                                 \
        for (; j < cnt; ++j) {                                            \
            int sA = cp[j];                                               \
            int4 hA = hrow[(size_t)sA * 8 + sub];                         \
            ACC1(hA);                                                     \
        }                                                                 \
        cp += cnt;                                                        \
    }

// =============== fused agg1 + GEMM2: hn2 = bf16((relu(agg(hn)+b1) @ W2) * dinv[row]) ===============
__global__ __launch_bounds__(256) void agg1_gemm2(
    const int* __restrict__ ofs, const int2* __restrict__ qcnt,
    const int* __restrict__ csr, const unsigned short* __restrict__ hnA,
    const float* __restrict__ dinv, const float* __restrict__ bias,
    const unsigned short* __restrict__ WfH, const unsigned short* __restrict__ WfL,
    unsigned short* __restrict__ hnB, int N)
{
    __shared__ unsigned short sH[32 * 72];
    int tid  = threadIdx.x;
    int lane = tid & 63, wave = tid >> 6;
    int grp  = lane >> 3, sub = lane & 7;
    int rowInBlk = wave * 8 + grp;
    int nodeBase = (int)blockIdx.x * 32;
    int node = nodeBase + rowInBlk;
    bool live = (node < N);

    const int4* hrow = (const int4*)hnA;
    float2 a0 = {0.f, 0.f}, a1 = {0.f, 0.f}, a2 = {0.f, 0.f}, a3 = {0.f, 0.f};

    int s0 = 0;
    unsigned qlo = 0, qhi = 0;
    if (live) {
        s0 = ofs[node];
        int2 qc = qcnt[node];
        qlo = (unsigned)qc.x; qhi = (unsigned)qc.y;
        int4 h = hrow[(size_t)node * 8 + sub];       // self loop (pre-scaled)
        ACC1(h);
    }

    const int* cp = csr + s0;
    BIN_GATHER_LOOP;

    {
        float dw = live ? dinv[node] : 0.f;
        float4 b0 = ((const float4*)bias)[sub * 2];
        float4 b1 = ((const float4*)bias)[sub * 2 + 1];
        float o0 = fmaxf(a0.x * dw + b0.x, 0.f);
        float o1 = fmaxf(a0.y * dw + b0.y, 0.f);
        float o2 = fmaxf(a1.x * dw + b0.z, 0.f);
        float o3 = fmaxf(a1.y * dw + b0.w, 0.f);
        float o4 = fmaxf(a2.x * dw + b1.x, 0.f);
        float o5 = fmaxf(a2.y * dw + b1.y, 0.f);
        float o6 = fmaxf(a3.x * dw + b1.z, 0.f);
        float o7 = fmaxf(a3.y * dw + b1.w, 0.f);
        unsigned r0 = (unsigned)f2bf(o0) | ((unsigned)f2bf(o1) << 16);
        unsigned r1 = (unsigned)f2bf(o2) | ((unsigned)f2bf(o3) << 16);
        unsigned r2 = (unsigned)f2bf(o4) | ((unsigned)f2bf(o5) << 16);
        unsigned r3 = (unsigned)f2bf(o6) | ((unsigned)f2bf(o7) << 16);
        *(int4*)&sH[rowInBlk * 72 + sub * 8] = make_int4((int)r0, (int)r1, (int)r2, (int)r3);
    }
    __syncthreads();

    if (wave < 2) {
        int g = lane >> 4, rl = lane & 15;
        f32x4 acc[4];
#pragma unroll
        for (int c = 0; c < 4; ++c) acc[c] = (f32x4){0.f, 0.f, 0.f, 0.f};

#pragma unroll
        for (int s = 0; s < 2; ++s) {
            short8 a = *(const short8*)&sH[(wave * 16 + rl) * 72 + 32 * s + 8 * g];
            short8 BH[4], BL[4];
#pragma unroll
            for (int c = 0; c < 4; ++c) {
                BH[c] = *(const short8*)(WfH + ((s * 4 + c) * 64 + lane) * 8);
                BL[c] = *(const short8*)(WfL + ((s * 4 + c) * 64 + lane) * 8);
            }
#pragma unroll
            for (int c = 0; c < 4; ++c)
                acc[c] = __builtin_amdgcn_mfma_f32_16x16x32_bf16(a, BH[c], acc[c], 0, 0, 0);
#pragma unroll
            for (int c = 0; c < 4; ++c)
                acc[c] = __builtin_amdgcn_mfma_f32_16x16x32_bf16(a, BL[c], acc[c], 0, 0, 0);
        }

#pragma unroll
        for (int r = 0; r < 4; ++r) {
            int row = nodeBase + wave * 16 + g * 4 + r;
            if (row < N) {
                float dv = dinv[row];
                unsigned short* hw = hnB + (size_t)row * D + rl;
#pragma unroll
                for (int c = 0; c < 4; ++c) hw[c * 16] = f2bf(acc[c][r] * dv);
            }
        }
    }
}

// =============== aggregate 2: one 8-lane group per node, 8 nodes per wave -> fp32 out ===============
__global__ __launch_bounds__(256) void aggregate_relu_f32(
    const int* __restrict__ ofs, const int2* __restrict__ qcnt,
    const int* __restrict__ csr, const unsigned short* __restrict__ hn,
    const float* __restrict__ dinv, const float* __restrict__ bias,
    float* __restrict__ outF, int N)
{
    int t    = blockIdx.x * 256 + threadIdx.x;
    int lane = threadIdx.x & 63;
    int grp  = lane >> 3, sub = lane & 7;
    int node = (t >> 6) * 8 + grp;
    bool live = (node < N);

    const int4* hrow = (const int4*)hn;
    float2 a0 = {0.f, 0.f}, a1 = {0.f, 0.f}, a2 = {0.f, 0.f}, a3 = {0.f, 0.f};

    int s0 = 0;
    unsigned qlo = 0, qhi = 0;
    if (live) {
        s0 = ofs[node];
        int2 qc = qcnt[node];
        qlo = (unsigned)qc.x; qhi = (unsigned)qc.y;
        int4 h = hrow[(size_t)node * 8 + sub];       // self loop (pre-scaled)
        ACC1(h);
    }

    const int* cp = csr + s0;
    BIN_GATHER_LOOP;

    if (live) {
        float dw = dinv[node];
        float4 b0 = ((const float4*)bias)[sub * 2];
        float4 b1 = ((const float4*)bias)[sub * 2 + 1];
        float o0 = fmaxf(a0.x * dw + b0.x, 0.f);
        float o1 = fmaxf(a0.y * dw + b0.y, 0.f);
        float o2 = fmaxf(a1.x * dw + b0.z, 0.f);
        float o3 = fmaxf(a1.y * dw + b0.w, 0.f);
        float o4 = fmaxf(a2.x * dw + b1.x, 0.f);
        float o5 = fmaxf(a2.y * dw + b1.y, 0.f);
        float o6 = fmaxf(a3.x * dw + b1.z, 0.f);
        float o7 = fmaxf(a3.y * dw + b1.w, 0.f);
        float4 v0 = make_float4(o0, o1, o2, o3);
        float4 v1 = make_float4(o4, o5, o6, o7);
        ((float4*)outF)[(size_t)node * 16 + sub * 2]     = v0;
        ((float4*)outF)[(size_t)node * 16 + sub * 2 + 1] = v1;
    }
}

// =============== launcher ===============

extern "C" void kernel_launch(void* const* d_in, const int* in_sizes, int n_in,
                              void* d_out, int out_size, void* d_ws, size_t ws_size,
                              hipStream_t stream) {
    const float* x   = (const float*)d_in[0];
    const int*   ei  = (const int*)d_in[1];   // [2, E] int32
    const float* W1  = (const float*)d_in[2];
    const float* b1  = (const float*)d_in[3];
    const float* W2  = (const float*)d_in[4];
    const float* b2  = (const float*)d_in[5];

    int N = in_sizes[0] / D;
    int E = in_sizes[1] / 2;
    const int* src = ei;
    const int* dst = ei + E;
    int NBK = (N + 255) >> 8;
    int per = (((E + NB_HIST - 1) / NB_HIST) + 3) & ~3;

    // workspace layout (bytes, ~44 MB).  qcnt reuses blockCounts/partial (dead after passB).
    char* ws = (char*)d_ws;
    int*            blockCounts = (int*)(ws + 0x00000000);  // NB_HIST*NBK
    int*            partial     = (int*)(ws + 0x00080000);  // NBK*NB_HIST
    int2*           qcnt        = (int2*)(ws + 0x00000000); // N int2 (reuses dead region)
    int*            totals      = (int*)(ws + 0x00100000);  // NBK
    int*            bofs        = (int*)(ws + 0x00110000);  // NBK
    int*            deg         = (int*)(ws + 0x00120000);  // N
    float*          dinv        = (float*)(ws + 0x00190000);// N
    int*            ofs         = (int*)(ws + 0x00200000);  // N
    int*            bucketed    = (int*)(ws + 0x00280000);  // E
    int*            csr         = (int*)(ws + 0x00A00000);  // E
    unsigned short* hnA         = (unsigned short*)(ws + 0x01100000); // N*D bf16 (12.8 MB)
    unsigned short* hnB         = (unsigned short*)(ws + 0x01D80000); // N*D bf16 (12.8 MB)
    unsigned short* WfH1        = (unsigned short*)(ws + 0x02A80000); // 4096 ushort each
    unsigned short* WfL1        = WfH1 + 4096;
    unsigned short* WfH2        = WfL1 + 4096;
    unsigned short* WfL2        = WfH2 + 4096;
    float*          outF        = (float*)d_out;

    int nb_G = (N + 63) / 64;                 // MFMA gemm: 64 rows/block
    int nb_A = (N + 31) / 32;                 // agg: 8 nodes/wave, 32/block

    // edge preprocessing first so dinv is ready before GEMM1
    passA_hist_wfrag<<<NB_HIST + 4, 256, 0, stream>>>(dst, blockCounts, E, per, NBK,
                                                      W1, W2, WfH1, WfL1, WfH2, WfL2);
    scan_cols<<<(NBK + 3) / 4, 256, 0, stream>>>(blockCounts, partial, totals, NBK);
    scan_buckets<<<1, 64, 0, stream>>>(totals, bofs, NBK);
    passB<<<NB_HIST, 256, 0, stream>>>(src, dst, bofs, partial, bucketed, E, per, NBK);
    build_csr<<<NBK, 256, 0, stream>>>(bucketed, bofs, totals, deg, dinv, ofs, qcnt, csr, N);

    // layer 1 GEMM with fused dinv[src] pre-scale
    gemm1_mfma<<<nb_G, 256, 0, stream>>>(x, WfH1, WfL1, dinv, hnA, N);
    // fused: layer-1 aggregate + relu + layer-2 GEMM (+ dinv pre-scale) -> hnB
    agg1_gemm2<<<nb_A, 256, 0, stream>>>(ofs, qcnt, csr, hnA, dinv, b1, WfH2, WfL2, hnB, N);
    // layer 2 aggregate -> final out (fp32, d_out)
    aggregate_relu_f32<<<nb_A, 256, 0, stream>>>(ofs, qcnt, csr, hnB, dinv, b2, outF, N);
}

// Round 8
// 198.974 us; speedup vs baseline: 1.7476x; 1.1771x over previous
//
#include <hip/hip_runtime.h>
#include <hip/hip_bf16.h>

#define D 64
#define NB_HIST 256          // partition blocks (fixed ranges, pass A == pass B)
#define MAXBK 512            // supports N <= 131072 (buckets of 256 nodes)
#define QSHIFT 14            // src bins of 16384 nodes (csr ordering only; loop is plain)

typedef float vfloat4 __attribute__((ext_vector_type(4)));
typedef short short8 __attribute__((ext_vector_type(8)));
typedef float f32x4 __attribute__((ext_vector_type(4)));

__device__ __forceinline__ unsigned short f2bf(float f) {
    union { float f; unsigned u; } v; v.f = f;
    unsigned r = (v.u + 0x7FFF + ((v.u >> 16) & 1)) >> 16;   // RNE
    return (unsigned short)r;
}
__device__ __forceinline__ unsigned short bftrunc(float f) {
    union { float f; unsigned u; } v; v.f = f;
    return (unsigned short)(v.u >> 16);                      // truncate (hi part of split)
}
__device__ __forceinline__ float bffrom(unsigned short h) {
    union { unsigned u; float f; } v; v.u = ((unsigned)h) << 16; return v.f;
}
__device__ __forceinline__ float bflo(unsigned u) {
    union { unsigned u; float f; } v; v.u = u << 16; return v.f;
}
__device__ __forceinline__ float bfhi(unsigned u) {
    union { unsigned u; float f; } v; v.u = u & 0xFFFF0000u; return v.f;
}

// =============== pass A: {per-block LDS bucket histogram} + {W-fragment precompute} ===============
__global__ __launch_bounds__(256) void passA_hist_wfrag(
    const int* __restrict__ dst, int* __restrict__ blockCounts, int E, int per, int NBK,
    const float* __restrict__ W1, const float* __restrict__ W2,
    unsigned short* __restrict__ WfH1, unsigned short* __restrict__ WfL1,
    unsigned short* __restrict__ WfH2, unsigned short* __restrict__ WfL2)
{
    int tid = threadIdx.x;

    if ((int)blockIdx.x < NB_HIST) {
        __shared__ int hist[MAXBK];
        for (int i = tid; i < NBK; i += 256) hist[i] = 0;
        __syncthreads();
        int lo = blockIdx.x * per, hi = min(E, lo + per);   // per % 4 == 0
        for (int i = lo + tid * 4; i < hi; i += 1024) {
            if (i + 3 < hi) {
                int4 d4 = *(const int4*)(dst + i);
                atomicAdd(&hist[d4.x >> 8], 1);
                atomicAdd(&hist[d4.y >> 8], 1);
                atomicAdd(&hist[d4.z >> 8], 1);
                atomicAdd(&hist[d4.w >> 8], 1);
            } else {
                for (int k = i; k < hi; ++k) atomicAdd(&hist[dst[k] >> 8], 1);
            }
        }
        __syncthreads();
        for (int i = tid; i < NBK; i += 256)
            blockCounts[(size_t)blockIdx.x * NBK + i] = hist[i];
        return;
    }

    // W-fragment precompute: 4 blocks, block b: w = b>>1 (W1/W2), combos [ (b&1)*4, +4 )
    int b = (int)blockIdx.x - NB_HIST;
    const float* Wsrc = (b >> 1) ? W2 : W1;
    unsigned short* fh = (b >> 1) ? WfH2 : WfH1;
    unsigned short* fl = (b >> 1) ? WfL2 : WfL1;
    int combo = (b & 1) * 4 + (tid >> 6);
    int lane = tid & 63;
    int s = combo >> 2, c = combo & 3, g = lane >> 4, rl = lane & 15;
#pragma unroll
    for (int j = 0; j < 8; ++j) {
        float v = Wsrc[(32 * s + 8 * g + j) * D + 16 * c + rl];
        unsigned short h = bftrunc(v);
        fh[combo * 512 + lane * 8 + j] = h;
        fl[combo * 512 + lane * 8 + j] = f2bf(v - bffrom(h));
    }
}

// =============== C1: per-bucket exclusive scan over the 256 blocks ===============
__global__ __launch_bounds__(256) void scan_cols(
    const int* __restrict__ blockCounts, int* __restrict__ partial,
    int* __restrict__ totals, int NBK)
{
    int wave = threadIdx.x >> 6, lane = threadIdx.x & 63;
    int k = blockIdx.x * 4 + wave;
    if (k >= NBK) return;
    int carry = 0;
    for (int base = 0; base < NB_HIST; base += 64) {
        int b = base + lane;
        int v = blockCounts[(size_t)b * NBK + k];
        int inc = v;
        for (int d = 1; d < 64; d <<= 1) {
            int t = __shfl_up(inc, d, 64);
            if (lane >= d) inc += t;
        }
        partial[(size_t)k * NB_HIST + b] = inc - v + carry;
        carry += __shfl(inc, 63, 64);
    }
    if (lane == 0) totals[k] = carry;
}

// =============== pass B: scatter edges into bucket-grouped order (LDS cursors) ===============
// bofs (exclusive scan of bucket totals) computed in-block by wave 0 -- no scan_buckets kernel.
__global__ __launch_bounds__(256) void passB(
    const int* __restrict__ src, const int* __restrict__ dst,
    const int* __restrict__ totals, const int* __restrict__ partial,
    int* __restrict__ bucketed, int E, int per, int NBK)
{
    __shared__ int cur[MAXBK];
    __shared__ int sBofs[MAXBK];
    int tid = threadIdx.x, b = blockIdx.x;

    if (tid < 64) {
        int carry = 0;
        for (int base = 0; base < NBK; base += 64) {
            int i = base + tid;
            int v = (i < NBK) ? totals[i] : 0;
            int inc = v;
            for (int d = 1; d < 64; d <<= 1) {
                int t = __shfl_up(inc, d, 64);
                if (tid >= d) inc += t;
            }
            if (i < NBK) sBofs[i] = inc - v + carry;
            carry += __shfl(inc, 63, 64);
        }
    }
    __syncthreads();
    for (int i = tid; i < NBK; i += 256)
        cur[i] = sBofs[i] + partial[(size_t)i * NB_HIST + b];
    __syncthreads();

    int lo = b * per, hi = min(E, lo + per);
    for (int i = lo + tid * 4; i < hi; i += 1024) {
        if (i + 3 < hi) {
            int4 d4 = *(const int4*)(dst + i);
            int4 s4 = *(const int4*)(src + i);
            int p0 = atomicAdd(&cur[d4.x >> 8], 1);
            int p1 = atomicAdd(&cur[d4.y >> 8], 1);
            int p2 = atomicAdd(&cur[d4.z >> 8], 1);
            int p3 = atomicAdd(&cur[d4.w >> 8], 1);
            bucketed[p0] = (s4.x << 8) | (d4.x & 255);
            bucketed[p1] = (s4.y << 8) | (d4.y & 255);
            bucketed[p2] = (s4.z << 8) | (d4.z & 255);
            bucketed[p3] = (s4.w << 8) | (d4.w & 255);
        } else {
            for (int k = i; k < hi; ++k) {
                int d = dst[k], s = src[k];
                int pos = atomicAdd(&cur[d >> 8], 1);
                bucketed[pos] = (s << 8) | (d & 255);
            }
        }
    }
}

// =============== level 2: per-bucket CSR build (src-bin-ordered lists) + deg/dinv/ofs ===============
// Each node's neighbor list is written grouped by src bin (src >> QSHIFT) -> ascending-ish src
// order for the gather loops (cache locality), consumed by a PLAIN loop (no per-bin phasing).
// e0 (bucket base) computed in-block by wave 0 -- no scan_buckets kernel.
__global__ __launch_bounds__(256) void build_csr(
    const int* __restrict__ bucketed, const int* __restrict__ totals,
    int* __restrict__ deg, float* __restrict__ dinv,
    int* __restrict__ ofs, int* __restrict__ csr, int N)
{
    __shared__ int h8[256 * 8];     // per-node per-bin counts, later reused as cursors
    __shared__ int scn[256];
    __shared__ int sE0;
    int tid = threadIdx.x, k = blockIdx.x;

    if (tid < 64) {
        int s = 0;
        for (int i = tid; i < k; i += 64) s += totals[i];
        for (int d = 32; d >= 1; d >>= 1) s += __shfl_xor(s, d, 64);
        if (tid == 0) sE0 = s;
    }
    for (int i = tid; i < 2048; i += 256) h8[i] = 0;
    __syncthreads();

    int e0 = sE0, e1 = e0 + totals[k];
    int node = k * 256 + tid;

    for (int i = e0 + tid; i < e1; i += 256) {
        int v = bucketed[i];
        atomicAdd(&h8[((v & 255) << 3) | ((unsigned)(v >> 8) >> QSHIFT)], 1);
    }
    __syncthreads();

    int c[8]; int mydeg = 0;
#pragma unroll
    for (int b = 0; b < 8; ++b) { c[b] = h8[tid * 8 + b]; mydeg += c[b]; }
    scn[tid] = mydeg;
    __syncthreads();
    for (int d2 = 1; d2 < 256; d2 <<= 1) {
        int t = (tid >= d2) ? scn[tid - d2] : 0;
        __syncthreads();
        scn[tid] += t;
        __syncthreads();
    }
    int myofs = scn[tid] - mydeg;

    if (node < N) {
        deg[node]  = mydeg;
        dinv[node] = rsqrtf((float)(mydeg + 1));
        ofs[node]  = e0 + myofs;
    }

    // per-node per-bin write cursors
    int run = myofs;
#pragma unroll
    for (int b = 0; b < 8; ++b) { h8[tid * 8 + b] = run; run += c[b]; }
    __syncthreads();
    for (int i = e0 + tid; i < e1; i += 256) {
        int v = bucketed[i];
        int s = v >> 8;
        int pos = atomicAdd(&h8[((v & 255) << 3) | ((unsigned)s >> QSHIFT)], 1);
        csr[e0 + pos] = s;
    }
}

// =============== GEMM1 (MFMA): hn = bf16((X @ W1) * dinv[row]) ===============
__global__ __launch_bounds__(256) void gemm1_mfma(
    const float* __restrict__ X,
    const unsigned short* __restrict__ WfH, const unsigned short* __restrict__ WfL,
    const float* __restrict__ dinv, unsigned short* __restrict__ hn, int N)
{
    int t = threadIdx.x, wave = t >> 6, lane = t & 63;
    int rowBase = (int)blockIdx.x * 64 + wave * 16;
    if (rowBase >= N) return;
    int g = lane >> 4, rl = lane & 15;

    short8 BH[2][4], BL[2][4];
#pragma unroll
    for (int s = 0; s < 2; ++s)
#pragma unroll
        for (int c = 0; c < 4; ++c) {
            BH[s][c] = *(const short8*)(WfH + ((s * 4 + c) * 64 + lane) * 8);
            BL[s][c] = *(const short8*)(WfL + ((s * 4 + c) * 64 + lane) * 8);
        }

    int arow = rowBase + rl; if (arow >= N) arow = N - 1;
    const float* xr = X + (size_t)arow * D;

    f32x4 acc[4];
#pragma unroll
    for (int c = 0; c < 4; ++c) acc[c] = (f32x4){0.f, 0.f, 0.f, 0.f};

#pragma unroll
    for (int s = 0; s < 2; ++s) {
        vfloat4 x0 = *(const vfloat4*)(xr + 32 * s + 8 * g);
        vfloat4 x1 = *(const vfloat4*)(xr + 32 * s + 8 * g + 4);
        short8 ah, al;
#pragma unroll
        for (int j = 0; j < 4; ++j) {
            unsigned short h0 = bftrunc(x0[j]);
            ah[j] = (short)h0; al[j] = (short)f2bf(x0[j] - bffrom(h0));
            unsigned short h1 = bftrunc(x1[j]);
            ah[j + 4] = (short)h1; al[j + 4] = (short)f2bf(x1[j] - bffrom(h1));
        }
#pragma unroll
        for (int c = 0; c < 4; ++c)
            acc[c] = __builtin_amdgcn_mfma_f32_16x16x32_bf16(ah, BH[s][c], acc[c], 0, 0, 0);
#pragma unroll
        for (int c = 0; c < 4; ++c)
            acc[c] = __builtin_amdgcn_mfma_f32_16x16x32_bf16(ah, BL[s][c], acc[c], 0, 0, 0);
#pragma unroll
        for (int c = 0; c < 4; ++c)
            acc[c] = __builtin_amdgcn_mfma_f32_16x16x32_bf16(al, BH[s][c], acc[c], 0, 0, 0);
    }

#pragma unroll
    for (int r = 0; r < 4; ++r) {
        int row = rowBase + g * 4 + r;
        if (row < N) {
            float dv = dinv[row];
            unsigned short* hr = hn + (size_t)row * D + rl;
#pragma unroll
            for (int c = 0; c < 4; ++c) hr[c * 16] = f2bf(acc[c][r] * dv);
        }
    }
}

// =============== fused agg1 + GEMM2: hn2 = bf16((relu(agg(hn)+b1) @ W2) * dinv[row]) ===============
// Phase 1: aggregate 32 nodes (8-lane groups, plain depth-4 gather pipeline) -> LDS bf16 tile.
// Phase 2: waves 0,1 each do one 16x64 MFMA tile (W2 split hi/lo), scale by dinv, write hn2.
__global__ __launch_bounds__(256) void agg1_gemm2(
    const int* __restrict__ ofs, const int* __restrict__ deg,
    const int* __restrict__ csr, const unsigned short* __restrict__ hnA,
    const float* __restrict__ dinv, const float* __restrict__ bias,
    const unsigned short* __restrict__ WfH, const unsigned short* __restrict__ WfL,
    unsigned short* __restrict__ hnB, int N)
{
    __shared__ unsigned short sH[32 * 72];
    int tid  = threadIdx.x;
    int lane = tid & 63, wave = tid >> 6;
    int grp  = lane >> 3, sub = lane & 7;
    int rowInBlk = wave * 8 + grp;
    int nodeBase = (int)blockIdx.x * 32;
    int node = nodeBase + rowInBlk;
    bool live = (node < N);

    const int4* hrow = (const int4*)hnA;
    float2 a0 = {0.f, 0.f}, a1 = {0.f, 0.f}, a2 = {0.f, 0.f}, a3 = {0.f, 0.f};

    int s0 = 0, cnt = 0;
    if (live) {
        s0  = ofs[node];
        cnt = deg[node];
        int4 h = hrow[(size_t)node * 8 + sub];       // self loop (pre-scaled)
        a0.x += bflo(h.x); a0.y += bfhi(h.x);
        a1.x += bflo(h.y); a1.y += bfhi(h.y);
        a2.x += bflo(h.z); a2.y += bfhi(h.z);
        a3.x += bflo(h.w); a3.y += bfhi(h.w);
    }

    const int* cp = csr + s0;
    int j = 0;
    for (; j + 3 < cnt; j += 4) {                    // 4 gathers in flight per lane
        int sA = cp[j], sB = cp[j + 1], sC = cp[j + 2], sD = cp[j + 3];
        int4 hA = hrow[(size_t)sA * 8 + sub];
        int4 hB = hrow[(size_t)sB * 8 + sub];
        int4 hC = hrow[(size_t)sC * 8 + sub];
        int4 hD = hrow[(size_t)sD * 8 + sub];
        a0.x += bflo(hA.x); a0.y += bfhi(hA.x);
        a1.x += bflo(hA.y); a1.y += bfhi(hA.y);
        a2.x += bflo(hA.z); a2.y += bfhi(hA.z);
        a3.x += bflo(hA.w); a3.y += bfhi(hA.w);
        a0.x += bflo(hB.x); a0.y += bfhi(hB.x);
        a1.x += bflo(hB.y); a1.y += bfhi(hB.y);
        a2.x += bflo(hB.z); a2.y += bfhi(hB.z);
        a3.x += bflo(hB.w); a3.y += bfhi(hB.w);
        a0.x += bflo(hC.x); a0.y += bfhi(hC.x);
        a1.x += bflo(hC.y); a1.y += bfhi(hC.y);
        a2.x += bflo(hC.z); a2.y += bfhi(hC.z);
        a3.x += bflo(hC.w); a3.y += bfhi(hC.w);
        a0.x += bflo(hD.x); a0.y += bfhi(hD.x);
        a1.x += bflo(hD.y); a1.y += bfhi(hD.y);
        a2.x += bflo(hD.z); a2.y += bfhi(hD.z);
        a3.x += bflo(hD.w); a3.y += bfhi(hD.w);
    }
    for (; j < cnt; ++j) {
        int sA = cp[j];
        int4 hA = hrow[(size_t)sA * 8 + sub];
        a0.x += bflo(hA.x); a0.y += bfhi(hA.x);
        a1.x += bflo(hA.y); a1.y += bfhi(hA.y);
        a2.x += bflo(hA.z); a2.y += bfhi(hA.z);
        a3.x += bflo(hA.w); a3.y += bfhi(hA.w);
    }

    {
        float dw = live ? dinv[node] : 0.f;
        float4 b0 = ((const float4*)bias)[sub * 2];
        float4 b1 = ((const float4*)bias)[sub * 2 + 1];
        float o0 = fmaxf(a0.x * dw + b0.x, 0.f);
        float o1 = fmaxf(a0.y * dw + b0.y, 0.f);
        float o2 = fmaxf(a1.x * dw + b0.z, 0.f);
        float o3 = fmaxf(a1.y * dw + b0.w, 0.f);
        float o4 = fmaxf(a2.x * dw + b1.x, 0.f);
        float o5 = fmaxf(a2.y * dw + b1.y, 0.f);
        float o6 = fmaxf(a3.x * dw + b1.z, 0.f);
        float o7 = fmaxf(a3.y * dw + b1.w, 0.f);
        unsigned r0 = (unsigned)f2bf(o0) | ((unsigned)f2bf(o1) << 16);
        unsigned r1 = (unsigned)f2bf(o2) | ((unsigned)f2bf(o3) << 16);
        unsigned r2 = (unsigned)f2bf(o4) | ((unsigned)f2bf(o5) << 16);
        unsigned r3 = (unsigned)f2bf(o6) | ((unsigned)f2bf(o7) << 16);
        *(int4*)&sH[rowInBlk * 72 + sub * 8] = make_int4((int)r0, (int)r1, (int)r2, (int)r3);
    }
    __syncthreads();

    if (wave < 2) {
        int g = lane >> 4, rl = lane & 15;
        f32x4 acc[4];
#pragma unroll
        for (int c = 0; c < 4; ++c) acc[c] = (f32x4){0.f, 0.f, 0.f, 0.f};

#pragma unroll
        for (int s = 0; s < 2; ++s) {
            short8 a = *(const short8*)&sH[(wave * 16 + rl) * 72 + 32 * s + 8 * g];
            short8 BH[4], BL[4];
#pragma unroll
            for (int c = 0; c < 4; ++c) {
                BH[c] = *(const short8*)(WfH + ((s * 4 + c) * 64 + lane) * 8);
                BL[c] = *(const short8*)(WfL + ((s * 4 + c) * 64 + lane) * 8);
            }
#pragma unroll
            for (int c = 0; c < 4; ++c)
                acc[c] = __builtin_amdgcn_mfma_f32_16x16x32_bf16(a, BH[c], acc[c], 0, 0, 0);
#pragma unroll
            for (int c = 0; c < 4; ++c)
                acc[c] = __builtin_amdgcn_mfma_f32_16x16x32_bf16(a, BL[c], acc[c], 0, 0, 0);
        }

#pragma unroll
        for (int r = 0; r < 4; ++r) {
            int row = nodeBase + wave * 16 + g * 4 + r;
            if (row < N) {
                float dv = dinv[row];
                unsigned short* hw = hnB + (size_t)row * D + rl;
#pragma unroll
                for (int c = 0; c < 4; ++c) hw[c * 16] = f2bf(acc[c][r] * dv);
            }
        }
    }
}

// =============== aggregate 2: one 8-lane group per node, 8 nodes per wave -> fp32 out ===============
__global__ __launch_bounds__(256) void aggregate_relu_f32(
    const int* __restrict__ ofs, const int* __restrict__ deg,
    const int* __restrict__ csr, const unsigned short* __restrict__ hn,
    const float* __restrict__ dinv, const float* __restrict__ bias,
    float* __restrict__ outF, int N)
{
    int t    = blockIdx.x * 256 + threadIdx.x;
    int lane = threadIdx.x & 63;
    int grp  = lane >> 3, sub = lane & 7;
    int node = (t >> 6) * 8 + grp;
    bool live = (node < N);

    const int4* hrow = (const int4*)hn;
    float2 a0 = {0.f, 0.f}, a1 = {0.f, 0.f}, a2 = {0.f, 0.f}, a3 = {0.f, 0.f};

    int s0 = 0, cnt = 0;
    if (live) {
        s0  = ofs[node];
        cnt = deg[node];
        int4 h = hrow[(size_t)node * 8 + sub];       // self loop (pre-scaled)
        a0.x += bflo(h.x); a0.y += bfhi(h.x);
        a1.x += bflo(h.y); a1.y += bfhi(h.y);
        a2.x += bflo(h.z); a2.y += bfhi(h.z);
        a3.x += bflo(h.w); a3.y += bfhi(h.w);
    }

    const int* cp = csr + s0;
    int j = 0;
    for (; j + 3 < cnt; j += 4) {                    // 4 gathers in flight per lane
        int sA = cp[j], sB = cp[j + 1], sC = cp[j + 2], sD = cp[j + 3];
        int4 hA = hrow[(size_t)sA * 8 + sub];
        int4 hB = hrow[(size_t)sB * 8 + sub];
        int4 hC = hrow[(size_t)sC * 8 + sub];
        int4 hD = hrow[(size_t)sD * 8 + sub];
        a0.x += bflo(hA.x); a0.y += bfhi(hA.x);
        a1.x += bflo(hA.y); a1.y += bfhi(hA.y);
        a2.x += bflo(hA.z); a2.y += bfhi(hA.z);
        a3.x += bflo(hA.w); a3.y += bfhi(hA.w);
        a0.x += bflo(hB.x); a0.y += bfhi(hB.x);
        a1.x += bflo(hB.y); a1.y += bfhi(hB.y);
        a2.x += bflo(hB.z); a2.y += bfhi(hB.z);
        a3.x += bflo(hB.w); a3.y += bfhi(hB.w);
        a0.x += bflo(hC.x); a0.y += bfhi(hC.x);
        a1.x += bflo(hC.y); a1.y += bfhi(hC.y);
        a2.x += bflo(hC.z); a2.y += bfhi(hC.z);
        a3.x += bflo(hC.w); a3.y += bfhi(hC.w);
        a0.x += bflo(hD.x); a0.y += bfhi(hD.x);
        a1.x += bflo(hD.y); a1.y += bfhi(hD.y);
        a2.x += bflo(hD.z); a2.y += bfhi(hD.z);
        a3.x += bflo(hD.w); a3.y += bfhi(hD.w);
    }
    for (; j < cnt; ++j) {
        int sA = cp[j];
        int4 hA = hrow[(size_t)sA * 8 + sub];
        a0.x += bflo(hA.x); a0.y += bfhi(hA.x);
        a1.x += bflo(hA.y); a1.y += bfhi(hA.y);
        a2.x += bflo(hA.z); a2.y += bfhi(hA.z);
        a3.x += bflo(hA.w); a3.y += bfhi(hA.w);
    }

    if (live) {
        float dw = dinv[node];
        float4 b0 = ((const float4*)bias)[sub * 2];
        float4 b1 = ((const float4*)bias)[sub * 2 + 1];
        float o0 = fmaxf(a0.x * dw + b0.x, 0.f);
        float o1 = fmaxf(a0.y * dw + b0.y, 0.f);
        float o2 = fmaxf(a1.x * dw + b0.z, 0.f);
        float o3 = fmaxf(a1.y * dw + b0.w, 0.f);
        float o4 = fmaxf(a2.x * dw + b1.x, 0.f);
        float o5 = fmaxf(a2.y * dw + b1.y, 0.f);
        float o6 = fmaxf(a3.x * dw + b1.z, 0.f);
        float o7 = fmaxf(a3.y * dw + b1.w, 0.f);
        float4 v0 = make_float4(o0, o1, o2, o3);
        float4 v1 = make_float4(o4, o5, o6, o7);
        ((float4*)outF)[(size_t)node * 16 + sub * 2]     = v0;
        ((float4*)outF)[(size_t)node * 16 + sub * 2 + 1] = v1;
    }
}

// =============== launcher ===============

extern "C" void kernel_launch(void* const* d_in, const int* in_sizes, int n_in,
                              void* d_out, int out_size, void* d_ws, size_t ws_size,
                              hipStream_t stream) {
    const float* x   = (const float*)d_in[0];
    const int*   ei  = (const int*)d_in[1];   // [2, E] int32
    const float* W1  = (const float*)d_in[2];
    const float* b1  = (const float*)d_in[3];
    const float* W2  = (const float*)d_in[4];
    const float* b2  = (const float*)d_in[5];

    int N = in_sizes[0] / D;
    int E = in_sizes[1] / 2;
    const int* src = ei;
    const int* dst = ei + E;
    int NBK = (N + 255) >> 8;
    int per = (((E + NB_HIST - 1) / NB_HIST) + 3) & ~3;

    // workspace layout (bytes, ~44 MB)
    char* ws = (char*)d_ws;
    int*            blockCounts = (int*)(ws + 0x00000000);  // NB_HIST*NBK
    int*            partial     = (int*)(ws + 0x00080000);  // NBK*NB_HIST
    int*            totals      = (int*)(ws + 0x00100000);  // NBK
    int*            deg         = (int*)(ws + 0x00120000);  // N
    float*          dinv        = (float*)(ws + 0x00190000);// N
    int*            ofs         = (int*)(ws + 0x00200000);  // N
    int*            bucketed    = (int*)(ws + 0x00280000);  // E
    int*            csr         = (int*)(ws + 0x00A00000);  // E
    unsigned short* hnA         = (unsigned short*)(ws + 0x01100000); // N*D bf16 (12.8 MB)
    unsigned short* hnB         = (unsigned short*)(ws + 0x01D80000); // N*D bf16 (12.8 MB)
    unsigned short* WfH1        = (unsigned short*)(ws + 0x02A80000); // 4096 ushort each
    unsigned short* WfL1        = WfH1 + 4096;
    unsigned short* WfH2        = WfL1 + 4096;
    unsigned short* WfL2        = WfH2 + 4096;
    float*          outF        = (float*)d_out;

    int nb_G = (N + 63) / 64;                 // MFMA gemm: 64 rows/block
    int nb_A = (N + 31) / 32;                 // agg: 8 nodes/wave, 32/block

    // edge preprocessing first so dinv is ready before GEMM1 (7 launches total)
    passA_hist_wfrag<<<NB_HIST + 4, 256, 0, stream>>>(dst, blockCounts, E, per, NBK,
                                                      W1, W2, WfH1, WfL1, WfH2, WfL2);
    scan_cols<<<(NBK + 3) / 4, 256, 0, stream>>>(blockCounts, partial, totals, NBK);
    passB<<<NB_HIST, 256, 0, stream>>>(src, dst, totals, partial, bucketed, E, per, NBK);
    build_csr<<<NBK, 256, 0, stream>>>(bucketed, totals, deg, dinv, ofs, csr, N);

    // layer 1 GEMM with fused dinv[src] pre-scale
    gemm1_mfma<<<nb_G, 256, 0, stream>>>(x, WfH1, WfL1, dinv, hnA, N);
    // fused: layer-1 aggregate + relu + layer-2 GEMM (+ dinv pre-scale) -> hnB
    agg1_gemm2<<<nb_A, 256, 0, stream>>>(ofs, deg, csr, hnA, dinv, b1, WfH2, WfL2, hnB, N);
    // layer 2 aggregate -> final out (fp32, d_out)
    aggregate_relu_f32<<<nb_A, 256, 0, stream>>>(ofs, deg, csr, hnB, dinv, b2, outF, N);
}